// Round 9
// baseline (1725.216 us; speedup 1.0000x reference)
//
#include <hip/hip_runtime.h>
#include <hip/hip_bf16.h>
#include <hip/hip_fp16.h>

// Problem: B=64, T=1024, INPUT=256, HIDDEN=512, OUTPUT=256
//   xh = x @ W_xh + b_h
//   h_t = tanh(h_{t-1} @ W_hh + xh_t)   (serial over t)
//   out = hs @ W_hy + b_y
//
// Round 11: win the register war by aligning ALL compile-time occupancy
// signals. Eight rounds of data show reported VGPR == 512/(waves-per-SIMD
// implied by static-LDS occupancy): 58.5KB LDS -> 128 regs (r5/r7), 2.5KB ->
// ~50 regs + scratch spill of asm-pinned W (r9/r10). launch_bounds/waves_per_eu
// alone never moved it. So: scan = 256 threads (4 waves) + 57.6 KB static LDS
// -> compile-time 2 WGs/CU -> 2 waves/SIMD -> 256-VGPR budget, consistent with
// launch_bounds(256,2) under BOTH arg semantics and waves_per_eu(2,2).
// Per-thread W (4-CU split) = 32 uint4 = 128 pinned VGPRs + ~60 working < 256.
// Lock-free u64 (tag|2xf16) exchange unchanged from round 9 (pairwise
// handshake: partner can't overwrite until we've consumed - mutual-dependency
// proof in r9). Runtime-indexed pointer arrays replaced by ternary selects.

#define BT 65536      // B*T
#define HID 512
#define NIN 256
#define NOUT 256
#define TSTEPS 1024
#define NBATCH 64

typedef _Float16 hf2_t __attribute__((ext_vector_type(2)));

__device__ __forceinline__ float fdot2(unsigned w, unsigned h, float acc) {
#if __has_builtin(__builtin_amdgcn_fdot2)
    return __builtin_amdgcn_fdot2(__builtin_bit_cast(hf2_t, w),
                                  __builtin_bit_cast(hf2_t, h), acc, false);
#else
    __half2 wv = __builtin_bit_cast(__half2, w);
    __half2 hv = __builtin_bit_cast(__half2, h);
    float2 wf = __half22float2(wv);
    float2 hf = __half22float2(hv);
    return acc + wf.x * hf.x + wf.y * hf.y;
#endif
}

__device__ __forceinline__ float dot4(uint4 w, uint4 h, float acc) {
    acc = fdot2(w.x, h.x, acc);
    acc = fdot2(w.y, h.y, acc);
    acc = fdot2(w.z, h.z, acc);
    acc = fdot2(w.w, h.w, acc);
    return acc;
}

__device__ __forceinline__ unsigned pack2h(float a, float b) {
    unsigned lo = (unsigned)__half_as_ushort(__float2half_rn(a));
    unsigned hi = (unsigned)__half_as_ushort(__float2half_rn(b));
    return lo | (hi << 16);
}

// cross-lane add via DPP (VALU pipe, no LDS).
// 0xB1 = quad_perm xor1, 0x4E = quad_perm xor2, 0x141 = row_half_mirror
// (after xor1+xor2, swaps the two quad-sums of each 8-lane group -> 8-reduce).
template <int CTRL>
__device__ __forceinline__ float dpp_add(float x) {
    int y = __builtin_amdgcn_mov_dpp(__float_as_int(x), CTRL, 0xF, 0xF, true);
    return x + __int_as_float(y);
}
template <int CTRL>
__device__ __forceinline__ float dpp_get(float x) {
    int y = __builtin_amdgcn_mov_dpp(__float_as_int(x), CTRL, 0xF, 0xF, true);
    return __int_as_float(y);
}

// tanh(x) = 1 - 2/(e^{2x}+1); e^{2x} via v_exp_f32, division via v_rcp_f32.
__device__ __forceinline__ float fast_tanh(float x) {
    float e = __builtin_amdgcn_exp2f(x * 2.8853900817779268f);   // 2*log2(e)
    return 1.0f - 2.0f * __builtin_amdgcn_rcpf(e + 1.0f);
}

// ---------- generic load/store helpers ----------
__device__ __forceinline__ float4 load4f(const float* p) {
    return *(const float4*)p;
}
__device__ __forceinline__ float4 load4f(const __half* p) {
    ushort4 u = *(const ushort4*)p;
    float4 r;
    r.x = __half2float(__ushort_as_half(u.x));
    r.y = __half2float(__ushort_as_half(u.y));
    r.z = __half2float(__ushort_as_half(u.z));
    r.w = __half2float(__ushort_as_half(u.w));
    return r;
}
__device__ __forceinline__ void store1(float* p, float v) { *p = v; }
__device__ __forceinline__ void store1(__half* p, float v) { *p = __float2half_rn(v); }

// ---------- pack W_hh (f32 [k][col]) into per-thread f16 blobs ----------
// Scan WG quarter q, thread t (g=t>>3 in 0..31, s=t&7): cols 128q+4g..+3,
// k in [64s, 64s+64). W uint4 i = c*8+j (c=0..3, j=0..7), word u:
// pack(W[64s+8j+2u][128q+4g+c], W[64s+8j+2u+1][...]).
// Layout wblob[(q*32+i)*256 + t] (uint4), coalesced on t.
// Also zeroes the 32768-u64 exchange buffer (per-launch tag reset).
__global__ __launch_bounds__(256)
void pack_w4_kernel(const float* __restrict__ W,
                    unsigned* __restrict__ wblob_w,
                    unsigned long long* __restrict__ exch) {
    int w = blockIdx.x * 256 + threadIdx.x;   // 0..131071
    int q = w >> 15;            // 0..3
    int r = w & 32767;
    int i = r >> 10;            // 0..31
    int r2 = r & 1023;
    int t = r2 >> 2, u = r2 & 3;   // t 0..255
    int g = t >> 3, s = t & 7;
    int c = i >> 3, j = i & 7;     // c 0..3
    int col = 128 * q + 4 * g + c;
    int k = 64 * s + 8 * j + 2 * u;
    unsigned val = pack2h(W[(size_t)k * HID + col], W[(size_t)(k + 1) * HID + col]);
    wblob_w[(size_t)((q * 32 + i) * 256 + t) * 4 + u] = val;
    if (w < 32768) exch[w] = 0ull;            // graph-replay-safe tag reset
}

// ---------- f32 tiled GEMM with bias: C[M,N] = A[M,K] @ B[K,N] + bias[N] ----------
// Used only for xh = x @ W_xh + b_h (precision feeds the recurrence).
template <typename AT, typename CT>
__global__ __launch_bounds__(256)
void gemm_bias_kernel(const AT* __restrict__ A, const float* __restrict__ B,
                      const float* __restrict__ bias, CT* __restrict__ C,
                      int M, int N, int K) {
    const int TM = 64, TN = 64, TK = 16;
    __shared__ float As[TK][TM];
    __shared__ float Bs[TK][TN + 4];

    int tid = threadIdx.x;
    int tx = tid & 15;
    int ty = tid >> 4;
    int row0 = blockIdx.x * TM;
    int col0 = blockIdx.y * TN;

    float c[4][4];
#pragma unroll
    for (int i = 0; i < 4; ++i)
#pragma unroll
        for (int j = 0; j < 4; ++j) c[i][j] = 0.f;

    for (int kk = 0; kk < K; kk += TK) {
        {
            int ar = tid >> 2;
            int ac = (tid & 3) * 4;
            float4 av = load4f(A + (size_t)(row0 + ar) * K + kk + ac);
            As[ac + 0][ar] = av.x;
            As[ac + 1][ar] = av.y;
            As[ac + 2][ar] = av.z;
            As[ac + 3][ar] = av.w;
        }
        {
            int br = tid >> 4;
            int bc = (tid & 15) * 4;
            float4 bv = *(const float4*)(B + (size_t)(kk + br) * N + col0 + bc);
            *(float4*)&Bs[br][bc] = bv;
        }
        __syncthreads();
#pragma unroll
        for (int k = 0; k < TK; ++k) {
            float4 a = *(const float4*)&As[k][ty * 4];
            float4 b = *(const float4*)&Bs[k][tx * 4];
            float av[4] = {a.x, a.y, a.z, a.w};
            float bv[4] = {b.x, b.y, b.z, b.w};
#pragma unroll
            for (int i = 0; i < 4; ++i)
#pragma unroll
                for (int j = 0; j < 4; ++j) c[i][j] += av[i] * bv[j];
        }
        __syncthreads();
    }

#pragma unroll
    for (int j = 0; j < 4; ++j) {
        float bb = bias[col0 + tx * 4 + j];
#pragma unroll
        for (int i = 0; i < 4; ++i) {
            int r = row0 + ty * 4 + i;
            int cc = col0 + tx * 4 + j;
            store1(&C[(size_t)r * N + cc], c[i][j] + bb);
        }
    }
}

// ---------- packed-f16 dot2 GEMM with bias (2 MACs/instr) ----------
// Used for out = hs @ W_hy + b_y: A is already f16; error does not recurse.
template <typename AT, typename CT>
__global__ __launch_bounds__(256)
void gemm_bias_f16_kernel(const AT* __restrict__ A, const float* __restrict__ B,
                          const float* __restrict__ bias, CT* __restrict__ C,
                          int M, int N, int K) {
    const int TM = 64, TN = 64, TK = 16;
    __shared__ unsigned Asp[TK / 2][TM];
    __shared__ unsigned Bsp[TK / 2][TN + 4];

    int tid = threadIdx.x;
    int tx = tid & 15;
    int ty = tid >> 4;
    int row0 = blockIdx.x * TM;
    int col0 = blockIdx.y * TN;

    float c[4][4];
#pragma unroll
    for (int i = 0; i < 4; ++i)
#pragma unroll
        for (int j = 0; j < 4; ++j) c[i][j] = 0.f;

    for (int kk = 0; kk < K; kk += TK) {
        {
            int ar = tid >> 2;
            int ac = (tid & 3) * 4;
            float4 av = load4f(A + (size_t)(row0 + ar) * K + kk + ac);
            Asp[(ac >> 1) + 0][ar] = pack2h(av.x, av.y);
            Asp[(ac >> 1) + 1][ar] = pack2h(av.z, av.w);
        }
        {
            int k2 = tid >> 5;
            int bc = (tid & 31) * 2;
            const float* b0 = B + (size_t)(kk + 2 * k2) * N + col0 + bc;
            const float* b1 = b0 + N;
            float2 r0 = *(const float2*)b0;
            float2 r1 = *(const float2*)b1;
            Bsp[k2][bc + 0] = pack2h(r0.x, r1.x);
            Bsp[k2][bc + 1] = pack2h(r0.y, r1.y);
        }
        __syncthreads();
#pragma unroll
        for (int k2 = 0; k2 < TK / 2; ++k2) {
            uint4 ap = *(const uint4*)&Asp[k2][ty * 4];
            uint4 bp = *(const uint4*)&Bsp[k2][tx * 4];
            unsigned av[4] = {ap.x, ap.y, ap.z, ap.w};
            unsigned bv[4] = {bp.x, bp.y, bp.z, bp.w};
#pragma unroll
            for (int i = 0; i < 4; ++i)
#pragma unroll
                for (int j = 0; j < 4; ++j) c[i][j] = fdot2(av[i], bv[j], c[i][j]);
        }
        __syncthreads();
    }

#pragma unroll
    for (int j = 0; j < 4; ++j) {
        float bb = bias[col0 + tx * 4 + j];
#pragma unroll
        for (int i = 0; i < 4; ++i) {
            int r = row0 + ty * 4 + i;
            int cc = col0 + tx * 4 + j;
            store1(&C[(size_t)r * N + cc], c[i][j] + bb);
        }
    }
}

// ---------- scan: 4 WGs per batch row, 256 threads, all-reg W ----------
// h2-index H (0..255) lives at LDS word (H>>5)*36 + (H&31) within a parity
// buffer of 288 words (72 uint4): slice s's 8 uint4 start at slot s*9 -> the
// 8 per-wave broadcast reads hit disjoint bank quads.
// exch word: [row][parity][quarter][m] u64 = (tag<<32) | packed 2xf16,
// m = 2g+(s>>1). tag = step+1, parity = (step+1)&1.
__global__ __launch_bounds__(256, 2)
__attribute__((amdgpu_waves_per_eu(2, 2)))
void rnn_scan4(const __half* __restrict__ xh,
               const uint4* __restrict__ wblob,            // [4][32][256]
               __half* __restrict__ hs,
               unsigned long long* __restrict__ exch) {    // [64][2][4][64]
    // 57.6 KB static LDS. Only the first 144 uint4 (h double-buffer) are
    // used; the full-size allocation makes the COMPILE-TIME occupancy
    // estimate 2 WGs/CU -> 2 waves/SIMD -> 256-VGPR budget (the lever that
    // r5/r7 hit by accident at 128 and r9/r10 lost at ~50). Runtime: grid
    // 256, >=2 LDS slots/CU -> always fully co-resident, deadlock-free.
    __shared__ __align__(16) uint4 big[3600];

    const int bid = blockIdx.x;          // 0..255
    const int row = bid & 63;            // batch row; group shares bid%8 (XCD)
    const int q   = bid >> 6;            // column quarter: cols [128q,128q+128)
    const int t = threadIdx.x;           // 0..255
    const int g = t >> 3, s = t & 7;     // col group (4 cols) / k-slice

    // whole weight slice: 32 uint4 = 128 VGPRs, pinned via asm identity
    // (asm results cannot be rematerialized; with a 256 budget they fit).
    uint4 W[32];
#pragma unroll
    for (int i = 0; i < 32; ++i) W[i] = wblob[(q * 32 + i) * 256 + t];
#pragma unroll
    for (int i = 0; i < 32; ++i) {
        asm volatile("" : "+v"(W[i].x), "+v"(W[i].y), "+v"(W[i].z), "+v"(W[i].w));
    }

    if (t < 144) big[t] = uint4{0u, 0u, 0u, 0u};   // zero both h parity buffers
    __syncthreads();

    const int col0 = 128 * q + 4 * g;    // lanes s<4 finalize col0+s
    const __half* xp = xh + (size_t)row * TSTEPS * HID + col0 + s;
    const int hw = 64 * q + 2 * g + (s >> 1);      // h2 word (s==0 / s==2 lanes)
    unsigned* hp32 = (unsigned*)hs + (size_t)row * TSTEPS * 256 + hw;
    const int wordC = (hw >> 5) * 36 + (hw & 31);
    unsigned long long* pub0 = exch + (((size_t)row * 2 + 0) * 4 + q) * 64 + (2 * g + (s >> 1));
    unsigned long long* pub1 = exch + (((size_t)row * 2 + 1) * 4 + q) * 64 + (2 * g + (s >> 1));
    // loader role: threads 0..191 fetch the 3 partner quarters (64 u64 each)
    const int m = t & 63;
    const int qa = t >> 6;                           // 0..2 for loaders
    const int Q = qa + (qa >= q ? 1 : 0);            // absolute partner quarter
    const unsigned long long* src0 = exch + (((size_t)row * 2 + 0) * 4 + Q) * 64 + m;
    const unsigned long long* src1 = exch + (((size_t)row * 2 + 1) * 4 + Q) * 64 + m;
    const int ldsw = ((64 * Q + m) >> 5) * 36 + ((64 * Q + m) & 31);

    for (int step = 0; step < TSTEPS; ++step) {
        const int par = step & 1;

        float xv = 0.f;
        if (s < 4) xv = __half2float(xp[(size_t)step * HID]);   // early issue

        if (step && t < 192) {
            // poll: a successful read carries the data (tag+payload in one u64)
            const unsigned long long* sp = par ? src1 : src0;   // no reg-array idx
            unsigned long long v = __hip_atomic_load(
                sp, __ATOMIC_RELAXED, __HIP_MEMORY_SCOPE_AGENT);
            while ((unsigned)(v >> 32) < (unsigned)step) {
                v = __hip_atomic_load(sp, __ATOMIC_RELAXED,
                                      __HIP_MEMORY_SCOPE_AGENT);
            }
            ((unsigned*)big)[par * 288 + ldsw] = (unsigned)v;
        }
        __syncthreads();

        // dots: 8 broadcast h uint4 (slice s) x 32 reg W -> 4 column sums
        const uint4* hv = &big[par * 72 + s * 9];
        float a0 = 0.f, a1 = 0.f, a2 = 0.f, a3 = 0.f;
#pragma unroll
        for (int j = 0; j < 8; ++j) {
            uint4 hj = hv[j];
            a0 = dot4(W[j],      hj, a0);
            a1 = dot4(W[8 + j],  hj, a1);
            a2 = dot4(W[16 + j], hj, a2);
            a3 = dot4(W[24 + j], hj, a3);
        }

        // 8-lane reduce on the VALU (xor1, xor2, half-mirror)
        a0 = dpp_add<0xB1>(a0); a0 = dpp_add<0x4E>(a0); a0 = dpp_add<0x141>(a0);
        a1 = dpp_add<0xB1>(a1); a1 = dpp_add<0x4E>(a1); a1 = dpp_add<0x141>(a1);
        a2 = dpp_add<0xB1>(a2); a2 = dpp_add<0x4E>(a2); a2 = dpp_add<0x141>(a2);
        a3 = dpp_add<0xB1>(a3); a3 = dpp_add<0x4E>(a3); a3 = dpp_add<0x141>(a3);

        if (s < 4) {
            float tot = (s == 0) ? a0 : (s == 1) ? a1 : (s == 2) ? a2 : a3;
            float hn = fast_tanh(tot + xv);
            float hi = dpp_get<0xB1>(hn);        // s0<-s1, s2<-s3 within quad
            if (!(s & 1)) {
                unsigned pv = pack2h(hn, hi);
                ((unsigned*)big)[(par ^ 1) * 288 + wordC] = pv;    // own next-state
                hp32[(size_t)step * 256] = pv;                     // hs output
                unsigned long long pubv =
                    ((unsigned long long)(unsigned)(step + 1) << 32) | pv;
                unsigned long long* pp = ((step + 1) & 1) ? pub1 : pub0;
                __hip_atomic_store(pp, pubv,
                                   __ATOMIC_RELAXED, __HIP_MEMORY_SCOPE_AGENT);
            }
        }
        // no end barrier: next step's __syncthreads orders the par^1 writes
    }
}

extern "C" void kernel_launch(void* const* d_in, const int* in_sizes, int n_in,
                              void* d_out, int out_size, void* d_ws, size_t ws_size,
                              hipStream_t stream) {
    const float* x    = (const float*)d_in[0];   // [64,1024,256]
    const float* W_xh = (const float*)d_in[1];   // [256,512]
    const float* W_hh = (const float*)d_in[2];   // [512,512]
    const float* b_h  = (const float*)d_in[3];   // [512]
    const float* W_hy = (const float*)d_in[4];   // [512,256]
    const float* b_y  = (const float*)d_in[5];   // [256]
    float* out = (float*)d_out;                  // [64,1024,256]

    char* ws = (char*)d_ws;
    unsigned* wblob = (unsigned*)ws;                              // 512 KiB
    unsigned long long* exch = (unsigned long long*)(ws + (512 << 10)); // 256 KiB
    __half* xh = (__half*)(ws + (1 << 20));                       // 64 MiB
    __half* hs = (__half*)(ws + (1 << 20) + (size_t)BT * HID * 2);// 64 MiB

    // 1) pack W_hh -> per-thread f16 blobs (256-thread 4-CU-split geometry)
    pack_w4_kernel<<<dim3(512), dim3(256), 0, stream>>>(W_hh, wblob, exch);

    // 2) xh = x @ W_xh + b_h   (f32 math -> f16 C; feeds the recurrence)
    gemm_bias_kernel<float, __half>
        <<<dim3(BT / 64, HID / 64), dim3(256), 0, stream>>>(x, W_xh, b_h, xh, BT, HID, NIN);

    // 3) scan: 256 WGs = 64 rows x 4 column-quarters, lock-free u64 exchange
    rnn_scan4<<<dim3(4 * NBATCH), dim3(256), 0, stream>>>(
        xh, (const uint4*)wblob, hs, exch);

    // 4) out = hs @ W_hy + b_y   (packed f16 dot2; error does not recurse)
    gemm_bias_f16_kernel<__half, float>
        <<<dim3(BT / 64, NOUT / 64), dim3(256), 0, stream>>>(hs, W_hy, b_y, out, BT, NOUT, HID);
}